// Round 1
// baseline (1338.296 us; speedup 1.0000x reference)
//
#include <hip/hip_runtime.h>
#include <hip/hip_bf16.h>

// Problem constants
#define Bb 32
#define Nn 1024
#define Ff 64
#define Tt 24

// Workspace layout (bytes)
//  LHS : (B*N*T) f32 at 0          = 3,145,728 B
//  RHS : (B*N*T) f32 at 3,145,728  = 3,145,728 B
//  MKEY: (B*N) u32 at 6,291,456    =   131,072 B
//  D0  : (N) f32  at 6,422,528     =     4,096 B
#define LHS_OFF  0
#define RHS_OFF  3145728
#define MKEY_OFF 6291456
#define D0_OFF   6422528

__device__ __forceinline__ unsigned fkey(float x) {
    unsigned u = __float_as_uint(x);
    return (u & 0x80000000u) ? ~u : (u | 0x80000000u);
}
__device__ __forceinline__ float keyToFloat(unsigned k) {
    unsigned u = (k & 0x80000000u) ? (k & 0x7FFFFFFFu) : ~k;
    return __uint_as_float(u);
}

// K1: fused lhs/rhs computation. One wave per (b,n) row.
// lhs[row][t] = sum_f (sum_t' x[row,f,t']*W1[t']) * W2[f,t]
// rhs[row][t] = sum_f x[row,f,t]*W3[f]
__global__ __launch_bounds__(256) void k1_lhs_rhs(
    const float* __restrict__ x, const float* __restrict__ W1,
    const float* __restrict__ W2, const float* __restrict__ W3,
    float* __restrict__ LHS, float* __restrict__ RHS) {
    __shared__ float sx[4][64][25];
    __shared__ float sy[4][64];
    __shared__ float sW1[24];
    __shared__ float sW2[64][24];
    __shared__ float sW3[64];
    int tid = threadIdx.x;
    if (tid < 24) sW1[tid] = W1[tid];
    if (tid < 64) sW3[tid] = W3[tid];
    for (int j = tid; j < 64 * 24; j += 256) sW2[j / 24][j % 24] = W2[j];
    __syncthreads();

    int w = tid >> 6, lane = tid & 63;
    int row = blockIdx.x * 4 + w;   // b*N+n
    const float* xr = x + (size_t)row * (Ff * Tt) + lane * Tt;
    float4 xv[6];
#pragma unroll
    for (int j = 0; j < 6; ++j) xv[j] = reinterpret_cast<const float4*>(xr)[j];
    float y = 0.f;
#pragma unroll
    for (int j = 0; j < 6; ++j) {
        y += xv[j].x * sW1[j * 4 + 0] + xv[j].y * sW1[j * 4 + 1] +
             xv[j].z * sW1[j * 4 + 2] + xv[j].w * sW1[j * 4 + 3];
    }
#pragma unroll
    for (int j = 0; j < 6; ++j) {
        sx[w][lane][j * 4 + 0] = xv[j].x;
        sx[w][lane][j * 4 + 1] = xv[j].y;
        sx[w][lane][j * 4 + 2] = xv[j].z;
        sx[w][lane][j * 4 + 3] = xv[j].w;
    }
    sy[w][lane] = y;
    __syncthreads();
    if (lane < 24) {
        int t = lane;
        float la = 0.f, ra = 0.f;
#pragma unroll 8
        for (int f = 0; f < 64; ++f) {
            ra += sx[w][f][t] * sW3[f];
            la += sy[w][f] * sW2[f][t];
        }
        LHS[(size_t)row * Tt + t] = la;
        RHS[(size_t)row * Tt + t] = ra;
    }
}

// K2: S[b,n,i] = sum_k V_s[i,k]*sigmoid(dot24(lhs[b,n,:],rhs[b,k,:]) + b_s[n,k])
// 128x128 output tile per block, KB=32, 8x8 microtile, fp32 vector FMA.
#define KB 32
__global__ __launch_bounds__(256) void k2_gemm(
    const float* __restrict__ LHS, const float* __restrict__ RHS,
    const float* __restrict__ V_s, const float* __restrict__ b_s,
    float* __restrict__ S) {
    __shared__ float Lst[24][132];       // lhs transposed [t][n]
    __shared__ float Rst[24][KB];        // rhs transposed [t][kk]
    __shared__ float As[KB][132];        // sig tile [kk][n]
    __shared__ float Bs[KB][132];        // V tile   [kk][i]

    int tid = threadIdx.x;
    int b = blockIdx.z;
    int n0 = blockIdx.y * 128;
    int i0 = blockIdx.x * 128;

    const float* lbase = LHS + ((size_t)b * Nn + n0) * Tt;
    for (int lin = tid; lin < 128 * Tt; lin += 256) {
        int r = lin / Tt, t = lin % Tt;
        Lst[t][r] = lbase[lin];
    }

    float acc[8][8] = {};
    int tx = tid & 15, ty = tid >> 4;      // GEMM microtile coords
    int an = (tid & 31) * 4;               // A-phase: 4 n-rows
    int ak = (tid >> 5) * 4;               // A-phase: 4 k-cols
    const float* rbase = RHS + (size_t)b * Nn * Tt;

    for (int k0 = 0; k0 < Nn; k0 += KB) {
        __syncthreads();   // protect As/Bs/Rst from previous iteration readers
        // load Rst (KB rows x 24)
        for (int lin = tid; lin < KB * Tt; lin += 256) {
            int r = lin / Tt, t = lin % Tt;
            Rst[t][r] = rbase[(size_t)(k0 + r) * Tt + t];
        }
        // load Bs: V_s[i0+i][k0+kk]
        for (int l4 = tid; l4 < 128 * (KB / 4); l4 += 256) {
            int i = l4 >> 3, k4 = (l4 & 7) << 2;
            float4 v = *(const float4*)&V_s[(size_t)(i0 + i) * Nn + k0 + k4];
            Bs[k4 + 0][i] = v.x; Bs[k4 + 1][i] = v.y;
            Bs[k4 + 2][i] = v.z; Bs[k4 + 3][i] = v.w;
        }
        __syncthreads();
        // A-phase: 4x4 product microtile over t
        float pacc[4][4] = {};
#pragma unroll
        for (int t = 0; t < 24; ++t) {
            float4 lv = *(const float4*)&Lst[t][an];
            float4 rv = *(const float4*)&Rst[t][ak];
            float lvv[4] = {lv.x, lv.y, lv.z, lv.w};
            float rvv[4] = {rv.x, rv.y, rv.z, rv.w};
#pragma unroll
            for (int r = 0; r < 4; ++r)
#pragma unroll
                for (int c = 0; c < 4; ++c) pacc[r][c] += lvv[r] * rvv[c];
        }
#pragma unroll
        for (int r = 0; r < 4; ++r) {
            float4 bs4 = *(const float4*)&b_s[(size_t)(n0 + an + r) * Nn + k0 + ak];
            float bsv[4] = {bs4.x, bs4.y, bs4.z, bs4.w};
#pragma unroll
            for (int c = 0; c < 4; ++c) {
                float p = pacc[r][c] + bsv[c];
                As[ak + c][an + r] = 1.f / (1.f + __expf(-p));
            }
        }
        __syncthreads();
        // main GEMM phase
#pragma unroll
        for (int kk = 0; kk < KB; ++kk) {
            float4 a0 = *(const float4*)&As[kk][ty * 4];
            float4 a1 = *(const float4*)&As[kk][ty * 4 + 64];
            float4 b0 = *(const float4*)&Bs[kk][tx * 4];
            float4 b1 = *(const float4*)&Bs[kk][tx * 4 + 64];
            float av[8] = {a0.x, a0.y, a0.z, a0.w, a1.x, a1.y, a1.z, a1.w};
            float bv[8] = {b0.x, b0.y, b0.z, b0.w, b1.x, b1.y, b1.z, b1.w};
#pragma unroll
            for (int r = 0; r < 8; ++r)
#pragma unroll
                for (int c = 0; c < 8; ++c) acc[r][c] += av[r] * bv[c];
        }
    }
    // epilogue: write S tile to d_out (used as S scratch)
#pragma unroll
    for (int r = 0; r < 8; ++r) {
        int nn = ty * 4 + (r & 3) + ((r >> 2) << 6);
        float4* op = (float4*)(S + ((size_t)(b * Nn + n0 + nn)) * Nn + i0 + tx * 4);
        op[0]  = make_float4(acc[r][0], acc[r][1], acc[r][2], acc[r][3]);
        op[16] = make_float4(acc[r][4], acc[r][5], acc[r][6], acc[r][7]);
    }
}

// K3: column max over n per (b,i) via ordered-uint atomicMax
__global__ __launch_bounds__(256) void k3_colmax(const float* __restrict__ S,
                                                 unsigned* __restrict__ Mkey) {
    int b = blockIdx.z;
    int i0 = blockIdx.x * 64;
    int nbase = blockIdx.y * 256;
    int ii = threadIdx.x & 63, g = threadIdx.x >> 6;
    const float* p = S + ((size_t)(b * Nn + nbase + g * 64)) * Nn + i0 + ii;
    float m = -3.402823466e38f;
#pragma unroll 4
    for (int n = 0; n < 64; ++n) m = fmaxf(m, p[(size_t)n * Nn]);
    __shared__ float red[4][64];
    red[g][ii] = m;
    __syncthreads();
    if (g == 0) {
        m = fmaxf(fmaxf(red[0][ii], red[1][ii]), fmaxf(red[2][ii], red[3][ii]));
        atomicMax(Mkey + b * Nn + i0 + ii, fkey(m));
    }
}

// K4: D0[i] = sum_n exp(S[0,n,i]-M[0,i])
__global__ __launch_bounds__(256) void k4_denom(const float* __restrict__ S,
                                                const unsigned* __restrict__ Mkey,
                                                float* __restrict__ D0) {
    int i0 = blockIdx.x * 64;
    int ii = threadIdx.x & 63, g = threadIdx.x >> 6;
    float M = keyToFloat(Mkey[i0 + ii]);
    const float* p = S + ((size_t)(g * 256)) * Nn + i0 + ii;
    float s = 0.f;
    for (int n = 0; n < 256; ++n) s += __expf(p[(size_t)n * Nn] - M);
    __shared__ float red[4][64];
    red[g][ii] = s;
    __syncthreads();
    if (g == 0) D0[i0 + ii] = (red[0][ii] + red[1][ii]) + (red[2][ii] + red[3][ii]);
}

// K5: out = exp(S - M[b,i]) / D0[i], in place on d_out
__global__ __launch_bounds__(256) void k5_final(float* __restrict__ S,
                                                const unsigned* __restrict__ Mkey,
                                                const float* __restrict__ D0) {
    const size_t total4 = (size_t)Bb * Nn * Nn / 4;  // 8,388,608
    for (size_t idx = (size_t)blockIdx.x * 256 + threadIdx.x; idx < total4;
         idx += (size_t)gridDim.x * 256) {
        size_t e = idx << 2;
        int i = (int)(e & (Nn - 1));
        int b = (int)(e >> 20);
        float4 s4 = ((const float4*)S)[idx];
        uint4 k4 = *(const uint4*)(Mkey + b * Nn + i);
        float4 d4 = *(const float4*)(D0 + i);
        float4 o;
        o.x = __expf(s4.x - keyToFloat(k4.x)) / d4.x;
        o.y = __expf(s4.y - keyToFloat(k4.y)) / d4.y;
        o.z = __expf(s4.z - keyToFloat(k4.z)) / d4.z;
        o.w = __expf(s4.w - keyToFloat(k4.w)) / d4.w;
        ((float4*)S)[idx] = o;
    }
}

extern "C" void kernel_launch(void* const* d_in, const int* in_sizes, int n_in,
                              void* d_out, int out_size, void* d_ws, size_t ws_size,
                              hipStream_t stream) {
    const float* x   = (const float*)d_in[0];
    const float* W1  = (const float*)d_in[1];
    const float* W2  = (const float*)d_in[2];
    const float* W3  = (const float*)d_in[3];
    const float* b_s = (const float*)d_in[4];
    const float* V_s = (const float*)d_in[5];
    float* out = (float*)d_out;

    char* ws = (char*)d_ws;
    float* LHS = (float*)(ws + LHS_OFF);
    float* RHS = (float*)(ws + RHS_OFF);
    unsigned* Mkey = (unsigned*)(ws + MKEY_OFF);
    float* D0 = (float*)(ws + D0_OFF);

    // K1: fused lhs/rhs
    k1_lhs_rhs<<<Bb * Nn / 4, 256, 0, stream>>>(x, W1, W2, W3, LHS, RHS);
    // K2: fused sigmoid-GEMM, S -> d_out
    k2_gemm<<<dim3(Nn / 128, Nn / 128, Bb), 256, 0, stream>>>(LHS, RHS, V_s, b_s, out);
    // init Mkey then K3 column max
    hipMemsetAsync(Mkey, 0, (size_t)Bb * Nn * sizeof(unsigned), stream);
    k3_colmax<<<dim3(Nn / 64, 4, Bb), 256, 0, stream>>>(out, Mkey);
    // K4 batch-0 denominators
    k4_denom<<<Nn / 64, 256, 0, stream>>>(out, Mkey, D0);
    // K5 final elementwise
    k5_final<<<2048, 256, 0, stream>>>(out, Mkey, D0);
}

// Round 2
// 311.886 us; speedup vs baseline: 4.2910x; 4.2910x over previous
//
#include <hip/hip_runtime.h>
#include <hip/hip_bf16.h>

// Problem constants
#define Bb 32
#define Nn 1024
#define Ff 64
#define Tt 24

// Workspace layout (bytes)
#define LHS_OFF  0
#define RHS_OFF  3145728
#define MKEY_OFF 6291456
#define D0_OFF   6422528
#define ABF_OFF  6426624ull            // sig bf16 [32768][1024] = 64 MiB
#define VB_OFF   73535488ull           // V bf16 [1024][1024] = 2 MiB
#define WS_NEED  75632640ull

typedef __attribute__((ext_vector_type(8))) short bf16x8;
typedef __attribute__((ext_vector_type(4))) float f32x4;

__device__ __forceinline__ unsigned fkey(float x) {
    unsigned u = __float_as_uint(x);
    return (u & 0x80000000u) ? ~u : (u | 0x80000000u);
}
__device__ __forceinline__ float keyToFloat(unsigned k) {
    unsigned u = (k & 0x80000000u) ? (k & 0x7FFFFFFFu) : ~k;
    return __uint_as_float(u);
}
__device__ __forceinline__ unsigned short f2bf(float f) {
    unsigned u = __float_as_uint(f);
    u += 0x7FFFu + ((u >> 16) & 1u);   // round-to-nearest-even
    return (unsigned short)(u >> 16);
}

// K1: fused lhs/rhs computation. One wave per (b,n) row.
__global__ __launch_bounds__(256) void k1_lhs_rhs(
    const float* __restrict__ x, const float* __restrict__ W1,
    const float* __restrict__ W2, const float* __restrict__ W3,
    float* __restrict__ LHS, float* __restrict__ RHS) {
    __shared__ float sx[4][64][25];
    __shared__ float sy[4][64];
    __shared__ float sW1[24];
    __shared__ float sW2[64][24];
    __shared__ float sW3[64];
    int tid = threadIdx.x;
    if (tid < 24) sW1[tid] = W1[tid];
    if (tid < 64) sW3[tid] = W3[tid];
    for (int j = tid; j < 64 * 24; j += 256) sW2[j / 24][j % 24] = W2[j];
    __syncthreads();

    int w = tid >> 6, lane = tid & 63;
    int row = blockIdx.x * 4 + w;   // b*N+n
    const float* xr = x + (size_t)row * (Ff * Tt) + lane * Tt;
    float4 xv[6];
#pragma unroll
    for (int j = 0; j < 6; ++j) xv[j] = reinterpret_cast<const float4*>(xr)[j];
    float y = 0.f;
#pragma unroll
    for (int j = 0; j < 6; ++j) {
        y += xv[j].x * sW1[j * 4 + 0] + xv[j].y * sW1[j * 4 + 1] +
             xv[j].z * sW1[j * 4 + 2] + xv[j].w * sW1[j * 4 + 3];
    }
#pragma unroll
    for (int j = 0; j < 6; ++j) {
        sx[w][lane][j * 4 + 0] = xv[j].x;
        sx[w][lane][j * 4 + 1] = xv[j].y;
        sx[w][lane][j * 4 + 2] = xv[j].z;
        sx[w][lane][j * 4 + 3] = xv[j].w;
    }
    sy[w][lane] = y;
    __syncthreads();
    if (lane < 24) {
        int t = lane;
        float la = 0.f, ra = 0.f;
#pragma unroll 8
        for (int f = 0; f < 64; ++f) {
            ra += sx[w][f][t] * sW3[f];
            la += sy[w][f] * sW2[f][t];
        }
        LHS[(size_t)row * Tt + t] = la;
        RHS[(size_t)row * Tt + t] = ra;
    }
}

// ---- k_vb: V_s fp32 -> bf16 (row-major [i][k] preserved) ----
__global__ __launch_bounds__(256) void k_vb(const float* __restrict__ V,
                                            unsigned* __restrict__ Vb2) {
    size_t idx = (size_t)blockIdx.x * 256 + threadIdx.x;   // 1M/4 float4s
    float4 v = ((const float4*)V)[idx];
    uint2 o;
    o.x = (unsigned)f2bf(v.x) | ((unsigned)f2bf(v.y) << 16);
    o.y = (unsigned)f2bf(v.z) | ((unsigned)f2bf(v.w) << 16);
    ((uint2*)Vb2)[idx] = o;
}

// ---- K2a: sig[b,n,k] = sigmoid(dot24(LHS[b,n,:],RHS[b,k,:]) + b_s[n,k]) -> bf16 ----
// grid (16 n-tiles, 2 k-halves, 32 b), 256 thr. Thread: n = t>>2, q = t&3 (k quarter).
__global__ __launch_bounds__(256) void k2a_sig(
    const float* __restrict__ LHS, const float* __restrict__ RHS,
    const float* __restrict__ b_s, unsigned short* __restrict__ Abf) {
    __shared__ float rst[24][68];   // rhs chunk transposed [t][k], padded
    int tid = threadIdx.x;
    int b = blockIdx.z;
    int n0 = blockIdx.x * 64;
    int kh = blockIdx.y * 512;
    int n = tid >> 2, q = tid & 3;

    float L[24];
    const float* lp = LHS + ((size_t)b * Nn + n0 + n) * Tt;
#pragma unroll
    for (int j = 0; j < 24; ++j) L[j] = lp[j];

    for (int kc = 0; kc < 512; kc += 64) {
        __syncthreads();
        const float* rp = RHS + ((size_t)b * Nn + kh + kc) * Tt;
        for (int e = tid; e < 64 * 24; e += 256) rst[e % 24][e / 24] = rp[e];
        __syncthreads();

        float P[16] = {};
#pragma unroll
        for (int j = 0; j < 24; ++j) {
            float Lj = L[j];
            const float4* rv = (const float4*)&rst[j][q * 16];
            float4 r0 = rv[0], r1 = rv[1], r2 = rv[2], r3 = rv[3];
            P[0]  += Lj * r0.x; P[1]  += Lj * r0.y; P[2]  += Lj * r0.z; P[3]  += Lj * r0.w;
            P[4]  += Lj * r1.x; P[5]  += Lj * r1.y; P[6]  += Lj * r1.z; P[7]  += Lj * r1.w;
            P[8]  += Lj * r2.x; P[9]  += Lj * r2.y; P[10] += Lj * r2.z; P[11] += Lj * r2.w;
            P[12] += Lj * r3.x; P[13] += Lj * r3.y; P[14] += Lj * r3.z; P[15] += Lj * r3.w;
        }
        const float* bp = &b_s[(size_t)(n0 + n) * Nn + kh + kc + q * 16];
        unsigned ow[8];
#pragma unroll
        for (int k4 = 0; k4 < 4; ++k4) {
            float4 bs = ((const float4*)bp)[k4];
            unsigned short s0 = f2bf(1.f / (1.f + __expf(-(P[k4 * 4 + 0] + bs.x))));
            unsigned short s1 = f2bf(1.f / (1.f + __expf(-(P[k4 * 4 + 1] + bs.y))));
            unsigned short s2 = f2bf(1.f / (1.f + __expf(-(P[k4 * 4 + 2] + bs.z))));
            unsigned short s3 = f2bf(1.f / (1.f + __expf(-(P[k4 * 4 + 3] + bs.w))));
            ow[k4 * 2 + 0] = (unsigned)s0 | ((unsigned)s1 << 16);
            ow[k4 * 2 + 1] = (unsigned)s2 | ((unsigned)s3 << 16);
        }
        unsigned short* op = Abf + ((size_t)b * Nn + n0 + n) * Nn + kh + kc + q * 16;
        ((uint4*)op)[0] = make_uint4(ow[0], ow[1], ow[2], ow[3]);
        ((uint4*)op)[1] = make_uint4(ow[4], ow[5], ow[6], ow[7]);
    }
}

// ---- K2b: bf16 MFMA GEMM. S[m][i] = sum_k A[m][k]*Vb[i][k], m=b*N+n ----
// 128x128 tile, BK=32, 4 waves (2x2), 4x4 16x16x32 fragments per wave.
__global__ __launch_bounds__(256) void k2b_mfma(
    const unsigned short* __restrict__ A, const unsigned short* __restrict__ Vb,
    float* __restrict__ S) {
    __shared__ unsigned short Al[128 * 32];   // [m][k] row-major, 8 KiB
    __shared__ unsigned short Bl[128 * 32];   // [i][k] row-major, 8 KiB
    int tid = threadIdx.x, w = tid >> 6, lane = tid & 63;
    int m0 = blockIdx.y * 128, i0 = blockIdx.x * 128;
    int wr = (w >> 1) * 64, wc = (w & 1) * 64;

    f32x4 acc[4][4] = {};
    int sr = lane >> 2;          // row within 16-row staging chunk
    int sk = (lane & 3) * 8;     // k element offset within BK
    const unsigned short* Abase = A + (size_t)m0 * 1024;
    const unsigned short* Bbase = Vb + (size_t)i0 * 1024;

    for (int kt = 0; kt < 1024; kt += 32) {
        __syncthreads();   // previous tile consumed
#pragma unroll
        for (int j = 0; j < 2; ++j) {
            int row = w * 32 + j * 16 + sr;
            __builtin_amdgcn_global_load_lds(
                (const __attribute__((address_space(1))) void*)(Abase + (size_t)row * 1024 + kt + sk),
                (__attribute__((address_space(3))) void*)(&Al[(w * 32 + j * 16) * 32]),
                16, 0, 0);
            __builtin_amdgcn_global_load_lds(
                (const __attribute__((address_space(1))) void*)(Bbase + (size_t)row * 1024 + kt + sk),
                (__attribute__((address_space(3))) void*)(&Bl[(w * 32 + j * 16) * 32]),
                16, 0, 0);
        }
        __syncthreads();   // compiler drains vmcnt(0) before barrier

        bf16x8 af[4], bfr[4];
#pragma unroll
        for (int xx = 0; xx < 4; ++xx) {
            af[xx]  = *(const bf16x8*)&Al[(wr + xx * 16 + (lane & 15)) * 32 + (lane >> 4) * 8];
            bfr[xx] = *(const bf16x8*)&Bl[(wc + xx * 16 + (lane & 15)) * 32 + (lane >> 4) * 8];
        }
#pragma unroll
        for (int mi = 0; mi < 4; ++mi)
#pragma unroll
            for (int ni = 0; ni < 4; ++ni)
                acc[mi][ni] = __builtin_amdgcn_mfma_f32_16x16x32_bf16(
                    af[mi], bfr[ni], acc[mi][ni], 0, 0, 0);
    }

    // epilogue: D col = lane&15 (i), row = (lane>>4)*4 + reg (m)
    int ic = i0 + wc + (lane & 15);
    int mrb = m0 + wr + (lane >> 4) * 4;
#pragma unroll
    for (int mi = 0; mi < 4; ++mi)
#pragma unroll
        for (int ni = 0; ni < 4; ++ni) {
#pragma unroll
            for (int r = 0; r < 4; ++r)
                S[(size_t)(mrb + mi * 16 + r) * 1024 + ic + ni * 16] = acc[mi][ni][r];
        }
}

// ---- fallback fp32 fused GEMM (round-1 path, used only if ws too small) ----
#define KB 32
__global__ __launch_bounds__(256) void k2_gemm(
    const float* __restrict__ LHS, const float* __restrict__ RHS,
    const float* __restrict__ V_s, const float* __restrict__ b_s,
    float* __restrict__ S) {
    __shared__ float Lst[24][132];
    __shared__ float Rst[24][KB];
    __shared__ float As[KB][132];
    __shared__ float Bs[KB][132];
    int tid = threadIdx.x;
    int b = blockIdx.z;
    int n0 = blockIdx.y * 128;
    int i0 = blockIdx.x * 128;
    const float* lbase = LHS + ((size_t)b * Nn + n0) * Tt;
    for (int lin = tid; lin < 128 * Tt; lin += 256) {
        int r = lin / Tt, t = lin % Tt;
        Lst[t][r] = lbase[lin];
    }
    float acc[8][8] = {};
    int tx = tid & 15, ty = tid >> 4;
    int an = (tid & 31) * 4;
    int ak = (tid >> 5) * 4;
    const float* rbase = RHS + (size_t)b * Nn * Tt;
    for (int k0 = 0; k0 < Nn; k0 += KB) {
        __syncthreads();
        for (int lin = tid; lin < KB * Tt; lin += 256) {
            int r = lin / Tt, t = lin % Tt;
            Rst[t][r] = rbase[(size_t)(k0 + r) * Tt + t];
        }
        for (int l4 = tid; l4 < 128 * (KB / 4); l4 += 256) {
            int i = l4 >> 3, k4 = (l4 & 7) << 2;
            float4 v = *(const float4*)&V_s[(size_t)(i0 + i) * Nn + k0 + k4];
            Bs[k4 + 0][i] = v.x; Bs[k4 + 1][i] = v.y;
            Bs[k4 + 2][i] = v.z; Bs[k4 + 3][i] = v.w;
        }
        __syncthreads();
        float pacc[4][4] = {};
#pragma unroll
        for (int t = 0; t < 24; ++t) {
            float4 lv = *(const float4*)&Lst[t][an];
            float4 rv = *(const float4*)&Rst[t][ak];
            float lvv[4] = {lv.x, lv.y, lv.z, lv.w};
            float rvv[4] = {rv.x, rv.y, rv.z, rv.w};
#pragma unroll
            for (int r = 0; r < 4; ++r)
#pragma unroll
                for (int c = 0; c < 4; ++c) pacc[r][c] += lvv[r] * rvv[c];
        }
#pragma unroll
        for (int r = 0; r < 4; ++r) {
            float4 bs4 = *(const float4*)&b_s[(size_t)(n0 + an + r) * Nn + k0 + ak];
            float bsv[4] = {bs4.x, bs4.y, bs4.z, bs4.w};
#pragma unroll
            for (int c = 0; c < 4; ++c) {
                float p = pacc[r][c] + bsv[c];
                As[ak + c][an + r] = 1.f / (1.f + __expf(-p));
            }
        }
        __syncthreads();
#pragma unroll
        for (int kk = 0; kk < KB; ++kk) {
            float4 a0 = *(const float4*)&As[kk][ty * 4];
            float4 a1 = *(const float4*)&As[kk][ty * 4 + 64];
            float4 b0 = *(const float4*)&Bs[kk][tx * 4];
            float4 b1 = *(const float4*)&Bs[kk][tx * 4 + 64];
            float av[8] = {a0.x, a0.y, a0.z, a0.w, a1.x, a1.y, a1.z, a1.w};
            float bv[8] = {b0.x, b0.y, b0.z, b0.w, b1.x, b1.y, b1.z, b1.w};
#pragma unroll
            for (int r = 0; r < 8; ++r)
#pragma unroll
                for (int c = 0; c < 8; ++c) acc[r][c] += av[r] * bv[c];
        }
    }
#pragma unroll
    for (int r = 0; r < 8; ++r) {
        int nn = ty * 4 + (r & 3) + ((r >> 2) << 6);
        float4* op = (float4*)(S + ((size_t)(b * Nn + n0 + nn)) * Nn + i0 + tx * 4);
        op[0]  = make_float4(acc[r][0], acc[r][1], acc[r][2], acc[r][3]);
        op[16] = make_float4(acc[r][4], acc[r][5], acc[r][6], acc[r][7]);
    }
}

// K3: column max over n per (b,i)
__global__ __launch_bounds__(256) void k3_colmax(const float* __restrict__ S,
                                                 unsigned* __restrict__ Mkey) {
    int b = blockIdx.z;
    int i0 = blockIdx.x * 64;
    int nbase = blockIdx.y * 256;
    int ii = threadIdx.x & 63, g = threadIdx.x >> 6;
    const float* p = S + ((size_t)(b * Nn + nbase + g * 64)) * Nn + i0 + ii;
    float m = -3.402823466e38f;
#pragma unroll 4
    for (int n = 0; n < 64; ++n) m = fmaxf(m, p[(size_t)n * Nn]);
    __shared__ float red[4][64];
    red[g][ii] = m;
    __syncthreads();
    if (g == 0) {
        m = fmaxf(fmaxf(red[0][ii], red[1][ii]), fmaxf(red[2][ii], red[3][ii]));
        atomicMax(Mkey + b * Nn + i0 + ii, fkey(m));
    }
}

// K4: D0[i] = sum_n exp(S[0,n,i]-M[0,i])
__global__ __launch_bounds__(256) void k4_denom(const float* __restrict__ S,
                                                const unsigned* __restrict__ Mkey,
                                                float* __restrict__ D0) {
    int i0 = blockIdx.x * 64;
    int ii = threadIdx.x & 63, g = threadIdx.x >> 6;
    float M = keyToFloat(Mkey[i0 + ii]);
    const float* p = S + ((size_t)(g * 256)) * Nn + i0 + ii;
    float s = 0.f;
    for (int n = 0; n < 256; ++n) s += __expf(p[(size_t)n * Nn] - M);
    __shared__ float red[4][64];
    red[g][ii] = s;
    __syncthreads();
    if (g == 0) D0[i0 + ii] = (red[0][ii] + red[1][ii]) + (red[2][ii] + red[3][ii]);
}

// K5: out = exp(S - M[b,i]) / D0[i], in place
__global__ __launch_bounds__(256) void k5_final(float* __restrict__ S,
                                                const unsigned* __restrict__ Mkey,
                                                const float* __restrict__ D0) {
    const size_t total4 = (size_t)Bb * Nn * Nn / 4;
    for (size_t idx = (size_t)blockIdx.x * 256 + threadIdx.x; idx < total4;
         idx += (size_t)gridDim.x * 256) {
        size_t e = idx << 2;
        int i = (int)(e & (Nn - 1));
        int b = (int)(e >> 20);
        float4 s4 = ((const float4*)S)[idx];
        uint4 k4 = *(const uint4*)(Mkey + b * Nn + i);
        float4 d4 = *(const float4*)(D0 + i);
        float4 o;
        o.x = __expf(s4.x - keyToFloat(k4.x)) / d4.x;
        o.y = __expf(s4.y - keyToFloat(k4.y)) / d4.y;
        o.z = __expf(s4.z - keyToFloat(k4.z)) / d4.z;
        o.w = __expf(s4.w - keyToFloat(k4.w)) / d4.w;
        ((float4*)S)[idx] = o;
    }
}

extern "C" void kernel_launch(void* const* d_in, const int* in_sizes, int n_in,
                              void* d_out, int out_size, void* d_ws, size_t ws_size,
                              hipStream_t stream) {
    const float* x   = (const float*)d_in[0];
    const float* W1  = (const float*)d_in[1];
    const float* W2  = (const float*)d_in[2];
    const float* W3  = (const float*)d_in[3];
    const float* b_s = (const float*)d_in[4];
    const float* V_s = (const float*)d_in[5];
    float* out = (float*)d_out;

    char* ws = (char*)d_ws;
    float* LHS = (float*)(ws + LHS_OFF);
    float* RHS = (float*)(ws + RHS_OFF);
    unsigned* Mkey = (unsigned*)(ws + MKEY_OFF);
    float* D0 = (float*)(ws + D0_OFF);

    k1_lhs_rhs<<<Bb * Nn / 4, 256, 0, stream>>>(x, W1, W2, W3, LHS, RHS);

    if (ws_size >= WS_NEED) {
        unsigned short* Abf = (unsigned short*)(ws + ABF_OFF);
        unsigned short* Vb  = (unsigned short*)(ws + VB_OFF);
        k_vb<<<1024, 256, 0, stream>>>(V_s, (unsigned*)Vb);
        k2a_sig<<<dim3(16, 2, 32), 256, 0, stream>>>(LHS, RHS, b_s, Abf);
        k2b_mfma<<<dim3(8, 256), 256, 0, stream>>>(Abf, Vb, out);
    } else {
        k2_gemm<<<dim3(Nn / 128, Nn / 128, Bb), 256, 0, stream>>>(LHS, RHS, V_s, b_s, out);
    }

    hipMemsetAsync(Mkey, 0, (size_t)Bb * Nn * sizeof(unsigned), stream);
    k3_colmax<<<dim3(Nn / 64, 4, Bb), 256, 0, stream>>>(out, Mkey);
    k4_denom<<<Nn / 64, 256, 0, stream>>>(out, Mkey, D0);
    k5_final<<<2048, 256, 0, stream>>>(out, Mkey, D0);
}

// Round 3
// 280.749 us; speedup vs baseline: 4.7669x; 1.1109x over previous
//
#include <hip/hip_runtime.h>
#include <hip/hip_bf16.h>

// Problem constants
#define Bb 32
#define Nn 1024
#define Ff 64
#define Tt 24

// Workspace layout (bytes)
#define LHS_OFF  0
#define RHS_OFF  3145728
#define MKEY_OFF 6291456
#define D0_OFF   6422528
#define ABF_OFF  6426624ull            // sig bf16 [32768][1024] = 64 MiB
#define VB_OFF   73535488ull           // V bf16 [1024][1024] = 2 MiB
#define WS_NEED  75632640ull

typedef __attribute__((ext_vector_type(8))) short bf16x8;
typedef __attribute__((ext_vector_type(4))) float f32x4;

__device__ __forceinline__ unsigned fkey(float x) {
    unsigned u = __float_as_uint(x);
    return (u & 0x80000000u) ? ~u : (u | 0x80000000u);
}
__device__ __forceinline__ float keyToFloat(unsigned k) {
    unsigned u = (k & 0x80000000u) ? (k & 0x7FFFFFFFu) : ~k;
    return __uint_as_float(u);
}
__device__ __forceinline__ unsigned short f2bf(float f) {
    unsigned u = __float_as_uint(f);
    u += 0x7FFFu + ((u >> 16) & 1u);   // round-to-nearest-even
    return (unsigned short)(u >> 16);
}

// K1: fused lhs/rhs computation. One wave per (b,n) row.
__global__ __launch_bounds__(256) void k1_lhs_rhs(
    const float* __restrict__ x, const float* __restrict__ W1,
    const float* __restrict__ W2, const float* __restrict__ W3,
    float* __restrict__ LHS, float* __restrict__ RHS) {
    __shared__ float sx[4][64][25];
    __shared__ float sy[4][64];
    __shared__ float sW1[24];
    __shared__ float sW2[64][24];
    __shared__ float sW3[64];
    int tid = threadIdx.x;
    if (tid < 24) sW1[tid] = W1[tid];
    if (tid < 64) sW3[tid] = W3[tid];
    for (int j = tid; j < 64 * 24; j += 256) sW2[j / 24][j % 24] = W2[j];
    __syncthreads();

    int w = tid >> 6, lane = tid & 63;
    int row = blockIdx.x * 4 + w;   // b*N+n
    const float* xr = x + (size_t)row * (Ff * Tt) + lane * Tt;
    float4 xv[6];
#pragma unroll
    for (int j = 0; j < 6; ++j) xv[j] = reinterpret_cast<const float4*>(xr)[j];
    float y = 0.f;
#pragma unroll
    for (int j = 0; j < 6; ++j) {
        y += xv[j].x * sW1[j * 4 + 0] + xv[j].y * sW1[j * 4 + 1] +
             xv[j].z * sW1[j * 4 + 2] + xv[j].w * sW1[j * 4 + 3];
    }
#pragma unroll
    for (int j = 0; j < 6; ++j) {
        sx[w][lane][j * 4 + 0] = xv[j].x;
        sx[w][lane][j * 4 + 1] = xv[j].y;
        sx[w][lane][j * 4 + 2] = xv[j].z;
        sx[w][lane][j * 4 + 3] = xv[j].w;
    }
    sy[w][lane] = y;
    __syncthreads();
    if (lane < 24) {
        int t = lane;
        float la = 0.f, ra = 0.f;
#pragma unroll 8
        for (int f = 0; f < 64; ++f) {
            ra += sx[w][f][t] * sW3[f];
            la += sy[w][f] * sW2[f][t];
        }
        LHS[(size_t)row * Tt + t] = la;
        RHS[(size_t)row * Tt + t] = ra;
    }
}

// ---- k_vb: V_s fp32 -> bf16 (row-major [i][k] preserved) ----
__global__ __launch_bounds__(256) void k_vb(const float* __restrict__ V,
                                            unsigned* __restrict__ Vb2) {
    size_t idx = (size_t)blockIdx.x * 256 + threadIdx.x;   // 1M/4 float4s
    float4 v = ((const float4*)V)[idx];
    uint2 o;
    o.x = (unsigned)f2bf(v.x) | ((unsigned)f2bf(v.y) << 16);
    o.y = (unsigned)f2bf(v.z) | ((unsigned)f2bf(v.w) << 16);
    ((uint2*)Vb2)[idx] = o;
}

// ---- K2a: sig[b,n,k] = sigmoid(dot24(LHS[b,n,:],RHS[b,k,:]) + b_s[n,k]) -> bf16 ----
__global__ __launch_bounds__(256) void k2a_sig(
    const float* __restrict__ LHS, const float* __restrict__ RHS,
    const float* __restrict__ b_s, unsigned short* __restrict__ Abf) {
    __shared__ float rst[24][68];   // rhs chunk transposed [t][k], padded
    int tid = threadIdx.x;
    int b = blockIdx.z;
    int n0 = blockIdx.x * 64;
    int kh = blockIdx.y * 512;
    int n = tid >> 2, q = tid & 3;

    float L[24];
    const float* lp = LHS + ((size_t)b * Nn + n0 + n) * Tt;
#pragma unroll
    for (int j = 0; j < 24; ++j) L[j] = lp[j];

    for (int kc = 0; kc < 512; kc += 64) {
        __syncthreads();
        const float* rp = RHS + ((size_t)b * Nn + kh + kc) * Tt;
        for (int e = tid; e < 64 * 24; e += 256) rst[e % 24][e / 24] = rp[e];
        __syncthreads();

        float P[16] = {};
#pragma unroll
        for (int j = 0; j < 24; ++j) {
            float Lj = L[j];
            const float4* rv = (const float4*)&rst[j][q * 16];
            float4 r0 = rv[0], r1 = rv[1], r2 = rv[2], r3 = rv[3];
            P[0]  += Lj * r0.x; P[1]  += Lj * r0.y; P[2]  += Lj * r0.z; P[3]  += Lj * r0.w;
            P[4]  += Lj * r1.x; P[5]  += Lj * r1.y; P[6]  += Lj * r1.z; P[7]  += Lj * r1.w;
            P[8]  += Lj * r2.x; P[9]  += Lj * r2.y; P[10] += Lj * r2.z; P[11] += Lj * r2.w;
            P[12] += Lj * r3.x; P[13] += Lj * r3.y; P[14] += Lj * r3.z; P[15] += Lj * r3.w;
        }
        const float* bp = &b_s[(size_t)(n0 + n) * Nn + kh + kc + q * 16];
        unsigned ow[8];
#pragma unroll
        for (int k4 = 0; k4 < 4; ++k4) {
            float4 bs = ((const float4*)bp)[k4];
            unsigned short s0 = f2bf(1.f / (1.f + __expf(-(P[k4 * 4 + 0] + bs.x))));
            unsigned short s1 = f2bf(1.f / (1.f + __expf(-(P[k4 * 4 + 1] + bs.y))));
            unsigned short s2 = f2bf(1.f / (1.f + __expf(-(P[k4 * 4 + 2] + bs.z))));
            unsigned short s3 = f2bf(1.f / (1.f + __expf(-(P[k4 * 4 + 3] + bs.w))));
            ow[k4 * 2 + 0] = (unsigned)s0 | ((unsigned)s1 << 16);
            ow[k4 * 2 + 1] = (unsigned)s2 | ((unsigned)s3 << 16);
        }
        unsigned short* op = Abf + ((size_t)b * Nn + n0 + n) * Nn + kh + kc + q * 16;
        ((uint4*)op)[0] = make_uint4(ow[0], ow[1], ow[2], ow[3]);
        ((uint4*)op)[1] = make_uint4(ow[4], ow[5], ow[6], ow[7]);
    }
}

// ---- K2b: bf16 MFMA GEMM + fused column-max.
// S[m][i] = sum_k A[m][k]*Vb[i][k]; 1-D grid 2048, XCD-aware swizzle (T1).
__global__ __launch_bounds__(256) void k2b_mfma(
    const unsigned short* __restrict__ A, const unsigned short* __restrict__ Vb,
    float* __restrict__ S, unsigned* __restrict__ Mkey) {
    __shared__ unsigned short Al[128 * 32];   // [m][k] row-major, 8 KiB
    __shared__ unsigned short Bl[128 * 32];   // [i][k] row-major, 8 KiB
    int tid = threadIdx.x, w = tid >> 6, lane = tid & 63;

    // T1 swizzle: XCD (bid%8) owns m-tiles [32*xcd, 32*xcd+32) x all 8 i-tiles.
    int bid = blockIdx.x;
    int L = ((bid & 7) << 8) + (bid >> 3);
    int i0 = (L & 7) * 128;
    int m0 = (L >> 3) * 128;
    int wr = (w >> 1) * 64, wc = (w & 1) * 64;

    f32x4 acc[4][4] = {};
    int sr = lane >> 2;          // row within 16-row staging chunk
    int sk = (lane & 3) * 8;     // k element offset within BK
    const unsigned short* Abase = A + (size_t)m0 * 1024;
    const unsigned short* Bbase = Vb + (size_t)i0 * 1024;

    for (int kt = 0; kt < 1024; kt += 32) {
        __syncthreads();   // previous tile consumed
#pragma unroll
        for (int j = 0; j < 2; ++j) {
            int row = w * 32 + j * 16 + sr;
            __builtin_amdgcn_global_load_lds(
                (const __attribute__((address_space(1))) void*)(Abase + (size_t)row * 1024 + kt + sk),
                (__attribute__((address_space(3))) void*)(&Al[(w * 32 + j * 16) * 32]),
                16, 0, 0);
            __builtin_amdgcn_global_load_lds(
                (const __attribute__((address_space(1))) void*)(Bbase + (size_t)row * 1024 + kt + sk),
                (__attribute__((address_space(3))) void*)(&Bl[(w * 32 + j * 16) * 32]),
                16, 0, 0);
        }
        __syncthreads();

        bf16x8 af[4], bfr[4];
#pragma unroll
        for (int xx = 0; xx < 4; ++xx) {
            af[xx]  = *(const bf16x8*)&Al[(wr + xx * 16 + (lane & 15)) * 32 + (lane >> 4) * 8];
            bfr[xx] = *(const bf16x8*)&Bl[(wc + xx * 16 + (lane & 15)) * 32 + (lane >> 4) * 8];
        }
#pragma unroll
        for (int mi = 0; mi < 4; ++mi)
#pragma unroll
            for (int ni = 0; ni < 4; ++ni)
                acc[mi][ni] = __builtin_amdgcn_mfma_f32_16x16x32_bf16(
                    af[mi], bfr[ni], acc[mi][ni], 0, 0, 0);
    }

    // epilogue: D col = lane&15 (i), row = (lane>>4)*4 + reg (m)
    int ic = i0 + wc + (lane & 15);
    int mrb = m0 + wr + (lane >> 4) * 4;
#pragma unroll
    for (int mi = 0; mi < 4; ++mi)
#pragma unroll
        for (int ni = 0; ni < 4; ++ni) {
#pragma unroll
            for (int r = 0; r < 4; ++r)
                S[(size_t)(mrb + mi * 16 + r) * 1024 + ic + ni * 16] = acc[mi][ni][r];
        }

    // fused column max: reduce acc over this block's 128 m-rows per column
    int bcol = m0 >> 10;   // batch index (m-tile never straddles a batch)
#pragma unroll
    for (int ni = 0; ni < 4; ++ni) {
        float mx = -3.402823466e38f;
#pragma unroll
        for (int mi = 0; mi < 4; ++mi)
#pragma unroll
            for (int r = 0; r < 4; ++r) mx = fmaxf(mx, acc[mi][ni][r]);
        mx = fmaxf(mx, __shfl_xor(mx, 16));
        mx = fmaxf(mx, __shfl_xor(mx, 32));
        if ((lane >> 4) == 0)
            atomicMax(&Mkey[bcol * Nn + ic + ni * 16], fkey(mx));
    }
}

// ---- fallback fp32 fused GEMM (used only if ws too small) ----
#define KB 32
__global__ __launch_bounds__(256) void k2_gemm(
    const float* __restrict__ LHS, const float* __restrict__ RHS,
    const float* __restrict__ V_s, const float* __restrict__ b_s,
    float* __restrict__ S) {
    __shared__ float Lst[24][132];
    __shared__ float Rst[24][KB];
    __shared__ float As[KB][132];
    __shared__ float Bs[KB][132];
    int tid = threadIdx.x;
    int b = blockIdx.z;
    int n0 = blockIdx.y * 128;
    int i0 = blockIdx.x * 128;
    const float* lbase = LHS + ((size_t)b * Nn + n0) * Tt;
    for (int lin = tid; lin < 128 * Tt; lin += 256) {
        int r = lin / Tt, t = lin % Tt;
        Lst[t][r] = lbase[lin];
    }
    float acc[8][8] = {};
    int tx = tid & 15, ty = tid >> 4;
    int an = (tid & 31) * 4;
    int ak = (tid >> 5) * 4;
    const float* rbase = RHS + (size_t)b * Nn * Tt;
    for (int k0 = 0; k0 < Nn; k0 += KB) {
        __syncthreads();
        for (int lin = tid; lin < KB * Tt; lin += 256) {
            int r = lin / Tt, t = lin % Tt;
            Rst[t][r] = rbase[(size_t)(k0 + r) * Tt + t];
        }
        for (int l4 = tid; l4 < 128 * (KB / 4); l4 += 256) {
            int i = l4 >> 3, k4 = (l4 & 7) << 2;
            float4 v = *(const float4*)&V_s[(size_t)(i0 + i) * Nn + k0 + k4];
            Bs[k4 + 0][i] = v.x; Bs[k4 + 1][i] = v.y;
            Bs[k4 + 2][i] = v.z; Bs[k4 + 3][i] = v.w;
        }
        __syncthreads();
        float pacc[4][4] = {};
#pragma unroll
        for (int t = 0; t < 24; ++t) {
            float4 lv = *(const float4*)&Lst[t][an];
            float4 rv = *(const float4*)&Rst[t][ak];
            float lvv[4] = {lv.x, lv.y, lv.z, lv.w};
            float rvv[4] = {rv.x, rv.y, rv.z, rv.w};
#pragma unroll
            for (int r = 0; r < 4; ++r)
#pragma unroll
                for (int c = 0; c < 4; ++c) pacc[r][c] += lvv[r] * rvv[c];
        }
#pragma unroll
        for (int r = 0; r < 4; ++r) {
            float4 bs4 = *(const float4*)&b_s[(size_t)(n0 + an + r) * Nn + k0 + ak];
            float bsv[4] = {bs4.x, bs4.y, bs4.z, bs4.w};
#pragma unroll
            for (int c = 0; c < 4; ++c) {
                float p = pacc[r][c] + bsv[c];
                As[ak + c][an + r] = 1.f / (1.f + __expf(-p));
            }
        }
        __syncthreads();
#pragma unroll
        for (int kk = 0; kk < KB; ++kk) {
            float4 a0 = *(const float4*)&As[kk][ty * 4];
            float4 a1 = *(const float4*)&As[kk][ty * 4 + 64];
            float4 b0 = *(const float4*)&Bs[kk][tx * 4];
            float4 b1 = *(const float4*)&Bs[kk][tx * 4 + 64];
            float av[8] = {a0.x, a0.y, a0.z, a0.w, a1.x, a1.y, a1.z, a1.w};
            float bv[8] = {b0.x, b0.y, b0.z, b0.w, b1.x, b1.y, b1.z, b1.w};
#pragma unroll
            for (int r = 0; r < 8; ++r)
#pragma unroll
                for (int c = 0; c < 8; ++c) acc[r][c] += av[r] * bv[c];
        }
    }
#pragma unroll
    for (int r = 0; r < 8; ++r) {
        int nn = ty * 4 + (r & 3) + ((r >> 2) << 6);
        float4* op = (float4*)(S + ((size_t)(b * Nn + n0 + nn)) * Nn + i0 + tx * 4);
        op[0]  = make_float4(acc[r][0], acc[r][1], acc[r][2], acc[r][3]);
        op[16] = make_float4(acc[r][4], acc[r][5], acc[r][6], acc[r][7]);
    }
}

// K3: column max over n per (b,i)  (fallback path only)
__global__ __launch_bounds__(256) void k3_colmax(const float* __restrict__ S,
                                                 unsigned* __restrict__ Mkey) {
    int b = blockIdx.z;
    int i0 = blockIdx.x * 64;
    int nbase = blockIdx.y * 256;
    int ii = threadIdx.x & 63, g = threadIdx.x >> 6;
    const float* p = S + ((size_t)(b * Nn + nbase + g * 64)) * Nn + i0 + ii;
    float m = -3.402823466e38f;
#pragma unroll 4
    for (int n = 0; n < 64; ++n) m = fmaxf(m, p[(size_t)n * Nn]);
    __shared__ float red[4][64];
    red[g][ii] = m;
    __syncthreads();
    if (g == 0) {
        m = fmaxf(fmaxf(red[0][ii], red[1][ii]), fmaxf(red[2][ii], red[3][ii]));
        atomicMax(Mkey + b * Nn + i0 + ii, fkey(m));
    }
}

// K4: D0[i] = sum_n exp(S[0,n,i]-M[0,i])
__global__ __launch_bounds__(256) void k4_denom(const float* __restrict__ S,
                                                const unsigned* __restrict__ Mkey,
                                                float* __restrict__ D0) {
    int i0 = blockIdx.x * 64;
    int ii = threadIdx.x & 63, g = threadIdx.x >> 6;
    float M = keyToFloat(Mkey[i0 + ii]);
    const float* p = S + ((size_t)(g * 256)) * Nn + i0 + ii;
    float s = 0.f;
    for (int n = 0; n < 256; ++n) s += __expf(p[(size_t)n * Nn] - M);
    __shared__ float red[4][64];
    red[g][ii] = s;
    __syncthreads();
    if (g == 0) D0[i0 + ii] = (red[0][ii] + red[1][ii]) + (red[2][ii] + red[3][ii]);
}

// K5: out = exp(S - M[b,i]) / D0[i], in place
__global__ __launch_bounds__(256) void k5_final(float* __restrict__ S,
                                                const unsigned* __restrict__ Mkey,
                                                const float* __restrict__ D0) {
    const size_t total4 = (size_t)Bb * Nn * Nn / 4;
    for (size_t idx = (size_t)blockIdx.x * 256 + threadIdx.x; idx < total4;
         idx += (size_t)gridDim.x * 256) {
        size_t e = idx << 2;
        int i = (int)(e & (Nn - 1));
        int b = (int)(e >> 20);
        float4 s4 = ((const float4*)S)[idx];
        uint4 k4 = *(const uint4*)(Mkey + b * Nn + i);
        float4 d4 = *(const float4*)(D0 + i);
        float4 o;
        o.x = __expf(s4.x - keyToFloat(k4.x)) / d4.x;
        o.y = __expf(s4.y - keyToFloat(k4.y)) / d4.y;
        o.z = __expf(s4.z - keyToFloat(k4.z)) / d4.z;
        o.w = __expf(s4.w - keyToFloat(k4.w)) / d4.w;
        ((float4*)S)[idx] = o;
    }
}

extern "C" void kernel_launch(void* const* d_in, const int* in_sizes, int n_in,
                              void* d_out, int out_size, void* d_ws, size_t ws_size,
                              hipStream_t stream) {
    const float* x   = (const float*)d_in[0];
    const float* W1  = (const float*)d_in[1];
    const float* W2  = (const float*)d_in[2];
    const float* W3  = (const float*)d_in[3];
    const float* b_s = (const float*)d_in[4];
    const float* V_s = (const float*)d_in[5];
    float* out = (float*)d_out;

    char* ws = (char*)d_ws;
    float* LHS = (float*)(ws + LHS_OFF);
    float* RHS = (float*)(ws + RHS_OFF);
    unsigned* Mkey = (unsigned*)(ws + MKEY_OFF);
    float* D0 = (float*)(ws + D0_OFF);

    k1_lhs_rhs<<<Bb * Nn / 4, 256, 0, stream>>>(x, W1, W2, W3, LHS, RHS);
    hipMemsetAsync(Mkey, 0, (size_t)Bb * Nn * sizeof(unsigned), stream);

    if (ws_size >= WS_NEED) {
        unsigned short* Abf = (unsigned short*)(ws + ABF_OFF);
        unsigned short* Vb  = (unsigned short*)(ws + VB_OFF);
        k_vb<<<1024, 256, 0, stream>>>(V_s, (unsigned*)Vb);
        k2a_sig<<<dim3(16, 2, 32), 256, 0, stream>>>(LHS, RHS, b_s, Abf);
        k2b_mfma<<<2048, 256, 0, stream>>>(Abf, Vb, out, Mkey);  // fused colmax
    } else {
        k2_gemm<<<dim3(Nn / 128, Nn / 128, Bb), 256, 0, stream>>>(LHS, RHS, V_s, b_s, out);
        k3_colmax<<<dim3(Nn / 64, 4, Bb), 256, 0, stream>>>(out, Mkey);
    }

    k4_denom<<<Nn / 64, 256, 0, stream>>>(out, Mkey, D0);
    k5_final<<<2048, 256, 0, stream>>>(out, Mkey, D0);
}

// Round 4
// 251.008 us; speedup vs baseline: 5.3317x; 1.1185x over previous
//
#include <hip/hip_runtime.h>
#include <hip/hip_bf16.h>

// Problem constants
#define Bb 32
#define Nn 1024
#define Ff 64
#define Tt 24

// Workspace layout (bytes)
#define LHS_OFF  0
#define RHS_OFF  3145728
#define MKEY_OFF 6291456
#define D0_OFF   6422528
#define ABF_OFF  6426624ull            // sig bf16 [32768][1024] = 64 MiB
#define VB_OFF   73535488ull           // V bf16 [1024][1024] = 2 MiB
#define WS_NEED  75632640ull

typedef __attribute__((ext_vector_type(8))) short bf16x8;
typedef __attribute__((ext_vector_type(4))) float f32x4;

__device__ __forceinline__ unsigned fkey(float x) {
    unsigned u = __float_as_uint(x);
    return (u & 0x80000000u) ? ~u : (u | 0x80000000u);
}
__device__ __forceinline__ float keyToFloat(unsigned k) {
    unsigned u = (k & 0x80000000u) ? (k & 0x7FFFFFFFu) : ~k;
    return __uint_as_float(u);
}
__device__ __forceinline__ unsigned short f2bf(float f) {
    unsigned u = __float_as_uint(f);
    u += 0x7FFFu + ((u >> 16) & 1u);   // round-to-nearest-even
    return (unsigned short)(u >> 16);
}

// K1: fused lhs/rhs computation. One wave per (b,n) row.
__global__ __launch_bounds__(256) void k1_lhs_rhs(
    const float* __restrict__ x, const float* __restrict__ W1,
    const float* __restrict__ W2, const float* __restrict__ W3,
    float* __restrict__ LHS, float* __restrict__ RHS) {
    __shared__ float sx[4][64][25];
    __shared__ float sy[4][64];
    __shared__ float sW1[24];
    __shared__ float sW2[64][24];
    __shared__ float sW3[64];
    int tid = threadIdx.x;
    if (tid < 24) sW1[tid] = W1[tid];
    if (tid < 64) sW3[tid] = W3[tid];
    for (int j = tid; j < 64 * 24; j += 256) sW2[j / 24][j % 24] = W2[j];
    __syncthreads();

    int w = tid >> 6, lane = tid & 63;
    int row = blockIdx.x * 4 + w;   // b*N+n
    const float* xr = x + (size_t)row * (Ff * Tt) + lane * Tt;
    float4 xv[6];
#pragma unroll
    for (int j = 0; j < 6; ++j) xv[j] = reinterpret_cast<const float4*>(xr)[j];
    float y = 0.f;
#pragma unroll
    for (int j = 0; j < 6; ++j) {
        y += xv[j].x * sW1[j * 4 + 0] + xv[j].y * sW1[j * 4 + 1] +
             xv[j].z * sW1[j * 4 + 2] + xv[j].w * sW1[j * 4 + 3];
    }
#pragma unroll
    for (int j = 0; j < 6; ++j) {
        sx[w][lane][j * 4 + 0] = xv[j].x;
        sx[w][lane][j * 4 + 1] = xv[j].y;
        sx[w][lane][j * 4 + 2] = xv[j].z;
        sx[w][lane][j * 4 + 3] = xv[j].w;
    }
    sy[w][lane] = y;
    __syncthreads();
    if (lane < 24) {
        int t = lane;
        float la = 0.f, ra = 0.f;
#pragma unroll 8
        for (int f = 0; f < 64; ++f) {
            ra += sx[w][f][t] * sW3[f];
            la += sy[w][f] * sW2[f][t];
        }
        LHS[(size_t)row * Tt + t] = la;
        RHS[(size_t)row * Tt + t] = ra;
    }
}

// ---- k_vb: V_s fp32 -> bf16 (row-major [i][k] preserved) ----
__global__ __launch_bounds__(256) void k_vb(const float* __restrict__ V,
                                            unsigned* __restrict__ Vb2) {
    size_t idx = (size_t)blockIdx.x * 256 + threadIdx.x;   // 1M/4 float4s
    float4 v = ((const float4*)V)[idx];
    uint2 o;
    o.x = (unsigned)f2bf(v.x) | ((unsigned)f2bf(v.y) << 16);
    o.y = (unsigned)f2bf(v.z) | ((unsigned)f2bf(v.w) << 16);
    ((uint2*)Vb2)[idx] = o;
}

// ---- K2a: sig[b,n,k] = sigmoid(dot24(LHS[b,n,:],RHS[b,k,:]) + b_s[n,k]) -> bf16 ----
__global__ __launch_bounds__(256) void k2a_sig(
    const float* __restrict__ LHS, const float* __restrict__ RHS,
    const float* __restrict__ b_s, unsigned short* __restrict__ Abf) {
    __shared__ float rst[24][68];   // rhs chunk transposed [t][k], padded
    int tid = threadIdx.x;
    int b = blockIdx.z;
    int n0 = blockIdx.x * 64;
    int kh = blockIdx.y * 512;
    int n = tid >> 2, q = tid & 3;

    float L[24];
    const float* lp = LHS + ((size_t)b * Nn + n0 + n) * Tt;
#pragma unroll
    for (int j = 0; j < 24; ++j) L[j] = lp[j];

    for (int kc = 0; kc < 512; kc += 64) {
        __syncthreads();
        const float* rp = RHS + ((size_t)b * Nn + kh + kc) * Tt;
        for (int e = tid; e < 64 * 24; e += 256) rst[e % 24][e / 24] = rp[e];
        __syncthreads();

        float P[16] = {};
#pragma unroll
        for (int j = 0; j < 24; ++j) {
            float Lj = L[j];
            const float4* rv = (const float4*)&rst[j][q * 16];
            float4 r0 = rv[0], r1 = rv[1], r2 = rv[2], r3 = rv[3];
            P[0]  += Lj * r0.x; P[1]  += Lj * r0.y; P[2]  += Lj * r0.z; P[3]  += Lj * r0.w;
            P[4]  += Lj * r1.x; P[5]  += Lj * r1.y; P[6]  += Lj * r1.z; P[7]  += Lj * r1.w;
            P[8]  += Lj * r2.x; P[9]  += Lj * r2.y; P[10] += Lj * r2.z; P[11] += Lj * r2.w;
            P[12] += Lj * r3.x; P[13] += Lj * r3.y; P[14] += Lj * r3.z; P[15] += Lj * r3.w;
        }
        const float* bp = &b_s[(size_t)(n0 + n) * Nn + kh + kc + q * 16];
        unsigned ow[8];
#pragma unroll
        for (int k4 = 0; k4 < 4; ++k4) {
            float4 bs = ((const float4*)bp)[k4];
            unsigned short s0 = f2bf(1.f / (1.f + __expf(-(P[k4 * 4 + 0] + bs.x))));
            unsigned short s1 = f2bf(1.f / (1.f + __expf(-(P[k4 * 4 + 1] + bs.y))));
            unsigned short s2 = f2bf(1.f / (1.f + __expf(-(P[k4 * 4 + 2] + bs.z))));
            unsigned short s3 = f2bf(1.f / (1.f + __expf(-(P[k4 * 4 + 3] + bs.w))));
            ow[k4 * 2 + 0] = (unsigned)s0 | ((unsigned)s1 << 16);
            ow[k4 * 2 + 1] = (unsigned)s2 | ((unsigned)s3 << 16);
        }
        unsigned short* op = Abf + ((size_t)b * Nn + n0 + n) * Nn + kh + kc + q * 16;
        ((uint4*)op)[0] = make_uint4(ow[0], ow[1], ow[2], ow[3]);
        ((uint4*)op)[1] = make_uint4(ow[4], ow[5], ow[6], ow[7]);
    }
}

// ---- K2b: 256x256-tile bf16 MFMA GEMM, 4-deep LDS ring, counted vmcnt. ----
// S[m][i] = sum_k A[m][k]*Vb[i][k]. 512 thr = 8 waves (2 m x 4 i), each 128x64 out.
// BK=32. LDS buf (per K-tile): A[256][32] + B[256][32] bf16, ring of 4 = 128 KiB.
// Swizzle: 16B-chunk c of row r stored at chunk c ^ ((r>>1)&3)  (inverse-swizzled
// global source + swizzled read; global_load_lds dest stays linear — rule 21).
__global__ __launch_bounds__(512, 2) void k2b_mfma256(
    const unsigned short* __restrict__ A, const unsigned short* __restrict__ Vb,
    float* __restrict__ S, unsigned* __restrict__ Mkey) {
    __shared__ __align__(16) unsigned short lds[4 * 16384 + 512];  // +1KB dummy @65536

    int tid = threadIdx.x, w = tid >> 6, lane = tid & 63;

    // T1: 512 blocks, XCD (bid&7) gets 64 contiguous tiles (16 m-tiles x 4 i-tiles)
    int bid = blockIdx.x;
    int L = ((bid & 7) << 6) + (bid >> 3);
    int i0 = (L & 3) * 256;
    int m0 = (L >> 2) * 256;
    int wr = w >> 2, wc = w & 3;

    const unsigned short* Abase = A + (size_t)m0 * 1024;
    const unsigned short* Bbase = Vb + (size_t)i0 * 1024;

    // ---- staging lane constants ----
    int srow = lane >> 2;                         // row within 16-row subtile
    int csrc = (lane & 3) ^ ((lane >> 3) & 3);    // inverse-swizzled source chunk
    // per-lane source element offset (row part + chunk part); k-tile adds st*32
    // A subtile j of this wave: rows 32*w + 16*j .. +15
    // ---- read lane constants ----
    int xor8 = ((lane >> 4) ^ (((lane & 15) >> 1) & 3)) * 8;  // shorts
    int aoff = (wr * 128 + (lane & 15)) * 32 + xor8;
    int boff = (wc * 64 + (lane & 15)) * 32 + xor8;

    unsigned short* dummy = lds + 65536;

#define STAGE_A(st, j, dst)                                                            \
    __builtin_amdgcn_global_load_lds(                                                  \
        (const __attribute__((address_space(1))) void*)(Abase +                        \
            (size_t)(32 * w + 16 * (j) + srow) * 1024 + (st) * 32 + csrc * 8),         \
        (__attribute__((address_space(3))) void*)(dst), 16, 0, 0)
#define STAGE_B(st, j, dst)                                                            \
    __builtin_amdgcn_global_load_lds(                                                  \
        (const __attribute__((address_space(1))) void*)(Bbase +                        \
            (size_t)(32 * w + 16 * (j) + srow) * 1024 + (st) * 32 + csrc * 8),         \
        (__attribute__((address_space(3))) void*)(dst), 16, 0, 0)

    // prologue: stage K-tiles 0,1,2 into ring bufs 0,1,2
#pragma unroll
    for (int t = 0; t < 3; ++t) {
        unsigned short* bufA = lds + t * 16384;
        unsigned short* bufB = bufA + 8192;
        STAGE_A(t, 0, bufA + (32 * w) * 32);
        STAGE_A(t, 1, bufA + (32 * w + 16) * 32);
        STAGE_B(t, 0, bufB + (32 * w) * 32);
        STAGE_B(t, 1, bufB + (32 * w + 16) * 32);
    }
    asm volatile("s_waitcnt vmcnt(8)\n\ts_barrier" ::: "memory");  // tile 0 resident

    f32x4 acc[8][4] = {};

    for (int t = 0; t < 32; ++t) {
        unsigned short* bufA = lds + (t & 3) * 16384;
        unsigned short* bufB = bufA + 8192;
        int st = t + 3;
        bool real = (st < 32);
        if (!real) st = 31;                      // clamp source (content irrelevant)
        unsigned short* nbA = real ? lds + ((t + 3) & 3) * 16384 : dummy;
        unsigned short* nbB = real ? nbA + 8192 : dummy;
        unsigned short* dA0 = real ? nbA + (32 * w) * 32 : dummy;
        unsigned short* dA1 = real ? nbA + (32 * w + 16) * 32 : dummy;
        unsigned short* dB0 = real ? nbB + (32 * w) * 32 : dummy;
        unsigned short* dB1 = real ? nbB + (32 * w + 16) * 32 : dummy;

        // ---- phase A: frags (A rows mh=0, all B) + stage A-subtiles of tile t+3
        bf16x8 a0[4], b0[4];
#pragma unroll
        for (int mi = 0; mi < 4; ++mi)
            a0[mi] = *(const bf16x8*)(bufA + aoff + mi * 512);
#pragma unroll
        for (int ni = 0; ni < 4; ++ni)
            b0[ni] = *(const bf16x8*)(bufB + boff + ni * 512);
        STAGE_A(st, 0, dA0);
        STAGE_A(st, 1, dA1);
        __builtin_amdgcn_s_setprio(1);
#pragma unroll
        for (int mi = 0; mi < 4; ++mi)
#pragma unroll
            for (int ni = 0; ni < 4; ++ni)
                acc[mi][ni] = __builtin_amdgcn_mfma_f32_16x16x32_bf16(
                    a0[mi], b0[ni], acc[mi][ni], 0, 0, 0);
        __builtin_amdgcn_s_setprio(0);

        // ---- phase B: frags (A rows mh=1) + stage B-subtiles of tile t+3
        bf16x8 a1[4];
#pragma unroll
        for (int mi = 0; mi < 4; ++mi)
            a1[mi] = *(const bf16x8*)(bufA + aoff + 2048 + mi * 512);
        STAGE_B(st, 0, dB0);
        STAGE_B(st, 1, dB1);
        __builtin_amdgcn_s_setprio(1);
#pragma unroll
        for (int mi = 0; mi < 4; ++mi)
#pragma unroll
            for (int ni = 0; ni < 4; ++ni)
                acc[4 + mi][ni] = __builtin_amdgcn_mfma_f32_16x16x32_bf16(
                    a1[mi], b0[ni], acc[4 + mi][ni], 0, 0, 0);
        __builtin_amdgcn_s_setprio(0);

        // tile boundary: force tile t+1 resident (8 newest loads may float),
        // publish to all waves. Never vmcnt(0) in the loop (T4).
        asm volatile("s_waitcnt vmcnt(8)\n\ts_barrier" ::: "memory");
    }
#undef STAGE_A
#undef STAGE_B

    // epilogue: D col = lane&15 (i), row = (lane>>4)*4 + reg (m)
    int ic = i0 + wc * 64 + (lane & 15);
    int mrb = m0 + wr * 128 + (lane >> 4) * 4;
#pragma unroll
    for (int mi8 = 0; mi8 < 8; ++mi8)
#pragma unroll
        for (int ni = 0; ni < 4; ++ni) {
            f32x4 v = acc[mi8][ni];
#pragma unroll
            for (int r = 0; r < 4; ++r)
                S[(size_t)(mrb + mi8 * 16 + r) * 1024 + ic + ni * 16] = v[r];
        }

    // fused column max over this block's 256 m-rows (per batch; tile never straddles)
    int bcol = m0 >> 10;
#pragma unroll
    for (int ni = 0; ni < 4; ++ni) {
        float mx = -3.402823466e38f;
#pragma unroll
        for (int mi8 = 0; mi8 < 8; ++mi8)
#pragma unroll
            for (int r = 0; r < 4; ++r) mx = fmaxf(mx, acc[mi8][ni][r]);
        mx = fmaxf(mx, __shfl_xor(mx, 16));
        mx = fmaxf(mx, __shfl_xor(mx, 32));
        if ((lane >> 4) == 0)
            atomicMax(&Mkey[bcol * Nn + ic + ni * 16], fkey(mx));
    }
}

// ---- fallback fp32 fused GEMM (used only if ws too small) ----
#define KB 32
__global__ __launch_bounds__(256) void k2_gemm(
    const float* __restrict__ LHS, const float* __restrict__ RHS,
    const float* __restrict__ V_s, const float* __restrict__ b_s,
    float* __restrict__ S) {
    __shared__ float Lst[24][132];
    __shared__ float Rst[24][KB];
    __shared__ float As[KB][132];
    __shared__ float Bs[KB][132];
    int tid = threadIdx.x;
    int b = blockIdx.z;
    int n0 = blockIdx.y * 128;
    int i0 = blockIdx.x * 128;
    const float* lbase = LHS + ((size_t)b * Nn + n0) * Tt;
    for (int lin = tid; lin < 128 * Tt; lin += 256) {
        int r = lin / Tt, t = lin % Tt;
        Lst[t][r] = lbase[lin];
    }
    float acc[8][8] = {};
    int tx = tid & 15, ty = tid >> 4;
    int an = (tid & 31) * 4;
    int ak = (tid >> 5) * 4;
    const float* rbase = RHS + (size_t)b * Nn * Tt;
    for (int k0 = 0; k0 < Nn; k0 += KB) {
        __syncthreads();
        for (int lin = tid; lin < KB * Tt; lin += 256) {
            int r = lin / Tt, t = lin % Tt;
            Rst[t][r] = rbase[(size_t)(k0 + r) * Tt + t];
        }
        for (int l4 = tid; l4 < 128 * (KB / 4); l4 += 256) {
            int i = l4 >> 3, k4 = (l4 & 7) << 2;
            float4 v = *(const float4*)&V_s[(size_t)(i0 + i) * Nn + k0 + k4];
            Bs[k4 + 0][i] = v.x; Bs[k4 + 1][i] = v.y;
            Bs[k4 + 2][i] = v.z; Bs[k4 + 3][i] = v.w;
        }
        __syncthreads();
        float pacc[4][4] = {};
#pragma unroll
        for (int t = 0; t < 24; ++t) {
            float4 lv = *(const float4*)&Lst[t][an];
            float4 rv = *(const float4*)&Rst[t][ak];
            float lvv[4] = {lv.x, lv.y, lv.z, lv.w};
            float rvv[4] = {rv.x, rv.y, rv.z, rv.w};
#pragma unroll
            for (int r = 0; r < 4; ++r)
#pragma unroll
                for (int c = 0; c < 4; ++c) pacc[r][c] += lvv[r] * rvv[c];
        }
#pragma unroll
        for (int r = 0; r < 4; ++r) {
            float4 bs4 = *(const float4*)&b_s[(size_t)(n0 + an + r) * Nn + k0 + ak];
            float bsv[4] = {bs4.x, bs4.y, bs4.z, bs4.w};
#pragma unroll
            for (int c = 0; c < 4; ++c) {
                float p = pacc[r][c] + bsv[c];
                As[ak + c][an + r] = 1.f / (1.f + __expf(-p));
            }
        }
        __syncthreads();
#pragma unroll
        for (int kk = 0; kk < KB; ++kk) {
            float4 a0 = *(const float4*)&As[kk][ty * 4];
            float4 a1 = *(const float4*)&As[kk][ty * 4 + 64];
            float4 b0 = *(const float4*)&Bs[kk][tx * 4];
            float4 b1 = *(const float4*)&Bs[kk][tx * 4 + 64];
            float av[8] = {a0.x, a0.y, a0.z, a0.w, a1.x, a1.y, a1.z, a1.w};
            float bv[8] = {b0.x, b0.y, b0.z, b0.w, b1.x, b1.y, b1.z, b1.w};
#pragma unroll
            for (int r = 0; r < 8; ++r)
#pragma unroll
                for (int c = 0; c < 8; ++c) acc[r][c] += av[r] * bv[c];
        }
    }
#pragma unroll
    for (int r = 0; r < 8; ++r) {
        int nn = ty * 4 + (r & 3) + ((r >> 2) << 6);
        float4* op = (float4*)(S + ((size_t)(b * Nn + n0 + nn)) * Nn + i0 + tx * 4);
        op[0]  = make_float4(acc[r][0], acc[r][1], acc[r][2], acc[r][3]);
        op[16] = make_float4(acc[r][4], acc[r][5], acc[r][6], acc[r][7]);
    }
}

// K3: column max over n per (b,i)  (fallback path only)
__global__ __launch_bounds__(256) void k3_colmax(const float* __restrict__ S,
                                                 unsigned* __restrict__ Mkey) {
    int b = blockIdx.z;
    int i0 = blockIdx.x * 64;
    int nbase = blockIdx.y * 256;
    int ii = threadIdx.x & 63, g = threadIdx.x >> 6;
    const float* p = S + ((size_t)(b * Nn + nbase + g * 64)) * Nn + i0 + ii;
    float m = -3.402823466e38f;
#pragma unroll 4
    for (int n = 0; n < 64; ++n) m = fmaxf(m, p[(size_t)n * Nn]);
    __shared__ float red[4][64];
    red[g][ii] = m;
    __syncthreads();
    if (g == 0) {
        m = fmaxf(fmaxf(red[0][ii], red[1][ii]), fmaxf(red[2][ii], red[3][ii]));
        atomicMax(Mkey + b * Nn + i0 + ii, fkey(m));
    }
}

// K4: D0[i] = sum_n exp(S[0,n,i]-M[0,i])
__global__ __launch_bounds__(256) void k4_denom(const float* __restrict__ S,
                                                const unsigned* __restrict__ Mkey,
                                                float* __restrict__ D0) {
    int i0 = blockIdx.x * 64;
    int ii = threadIdx.x & 63, g = threadIdx.x >> 6;
    float M = keyToFloat(Mkey[i0 + ii]);
    const float* p = S + ((size_t)(g * 256)) * Nn + i0 + ii;
    float s = 0.f;
    for (int n = 0; n < 256; ++n) s += __expf(p[(size_t)n * Nn] - M);
    __shared__ float red[4][64];
    red[g][ii] = s;
    __syncthreads();
    if (g == 0) D0[i0 + ii] = (red[0][ii] + red[1][ii]) + (red[2][ii] + red[3][ii]);
}

// K5: out = exp(S - M[b,i]) / D0[i], in place
__global__ __launch_bounds__(256) void k5_final(float* __restrict__ S,
                                                const unsigned* __restrict__ Mkey,
                                                const float* __restrict__ D0) {
    const size_t total4 = (size_t)Bb * Nn * Nn / 4;
    for (size_t idx = (size_t)blockIdx.x * 256 + threadIdx.x; idx < total4;
         idx += (size_t)gridDim.x * 256) {
        size_t e = idx << 2;
        int i = (int)(e & (Nn - 1));
        int b = (int)(e >> 20);
        float4 s4 = ((const float4*)S)[idx];
        uint4 k4 = *(const uint4*)(Mkey + b * Nn + i);
        float4 d4 = *(const float4*)(D0 + i);
        float4 o;
        o.x = __expf(s4.x - keyToFloat(k4.x)) / d4.x;
        o.y = __expf(s4.y - keyToFloat(k4.y)) / d4.y;
        o.z = __expf(s4.z - keyToFloat(k4.z)) / d4.z;
        o.w = __expf(s4.w - keyToFloat(k4.w)) / d4.w;
        ((float4*)S)[idx] = o;
    }
}

extern "C" void kernel_launch(void* const* d_in, const int* in_sizes, int n_in,
                              void* d_out, int out_size, void* d_ws, size_t ws_size,
                              hipStream_t stream) {
    const float* x   = (const float*)d_in[0];
    const float* W1  = (const float*)d_in[1];
    const float* W2  = (const float*)d_in[2];
    const float* W3  = (const float*)d_in[3];
    const float* b_s = (const float*)d_in[4];
    const float* V_s = (const float*)d_in[5];
    float* out = (float*)d_out;

    char* ws = (char*)d_ws;
    float* LHS = (float*)(ws + LHS_OFF);
    float* RHS = (float*)(ws + RHS_OFF);
    unsigned* Mkey = (unsigned*)(ws + MKEY_OFF);
    float* D0 = (float*)(ws + D0_OFF);

    k1_lhs_rhs<<<Bb * Nn / 4, 256, 0, stream>>>(x, W1, W2, W3, LHS, RHS);
    hipMemsetAsync(Mkey, 0, (size_t)Bb * Nn * sizeof(unsigned), stream);

    if (ws_size >= WS_NEED) {
        unsigned short* Abf = (unsigned short*)(ws + ABF_OFF);
        unsigned short* Vb  = (unsigned short*)(ws + VB_OFF);
        k_vb<<<1024, 256, 0, stream>>>(V_s, (unsigned*)Vb);
        k2a_sig<<<dim3(16, 2, 32), 256, 0, stream>>>(LHS, RHS, b_s, Abf);
        k2b_mfma256<<<512, 512, 0, stream>>>(Abf, Vb, out, Mkey);  // fused colmax
    } else {
        k2_gemm<<<dim3(Nn / 128, Nn / 128, Bb), 256, 0, stream>>>(LHS, RHS, V_s, b_s, out);
        k3_colmax<<<dim3(Nn / 64, 4, Bb), 256, 0, stream>>>(out, Mkey);
    }

    k4_denom<<<Nn / 64, 256, 0, stream>>>(out, Mkey, D0);
    k5_final<<<2048, 256, 0, stream>>>(out, Mkey, D0);
}